// Round 2
// baseline (127.378 us; speedup 1.0000x reference)
//
#include <hip/hip_runtime.h>
#include <math.h>

// LipschitzNorm: E=800000 edges, N=50000 nodes, H=4 heads, D=32 dims (fp32).
// out[e,h] = alpha[e,h] / (natt[h] * sqrt(g[e] + ||x[e,h]||^2) + EPS)
//   natt[h] = 4 * ||concat(att_l[h], att_r[h])||
//   g[e]    = segment_max(||x||^2, index).flat[index[e]]   (faithful view(-1,1) bug)

static constexpr int   H_        = 4;
static constexpr int   D_        = 32;
static constexpr int   N_NODES   = 50000;
static constexpr float ATT_NORM_ = 4.0f;
static constexpr float EPS_      = 1e-12f;

// Pass A (coalesced): one float4 per thread. Lane i of a wave reads 16B at
// base+i*16 -> 1KiB contiguous per wave, every byte used exactly once (no L1
// reuse needed, unlike the 128B-strided pair-per-thread version which
// amplified L2 traffic ~8x). Each (e,h) pair = 8 consecutive float4s = one
// aligned 8-lane group; 3-step shfl_xor butterfly reduces within the group.
__global__ void __launch_bounds__(256)
k_norm_scatter(const float* __restrict__ x,
               const int* __restrict__ index,
               const float* __restrict__ att_l,
               const float* __restrict__ att_r,
               float* __restrict__ max_norm,   // [N*H], pre-zeroed
               float* __restrict__ norm_x,     // [E*H]
               float* __restrict__ natt,       // [H]
               int total_f4) {                 // EH * 8
    if (blockIdx.x == 0 && threadIdx.x < H_) {
        const int h = threadIdx.x;
        float s = 0.f;
        #pragma unroll
        for (int d = 0; d < D_; ++d) {
            const float a = att_l[h * D_ + d];
            const float b = att_r[h * D_ + d];
            s += a * a + b * b;
        }
        natt[h] = ATT_NORM_ * sqrtf(s);
    }
    const int f = blockIdx.x * blockDim.x + threadIdx.x;   // float4 index
    if (f >= total_f4) return;

    const float4 v = reinterpret_cast<const float4*>(x)[f];
    float s = v.x * v.x + v.y * v.y + v.z * v.z + v.w * v.w;
    // butterfly over the 8-lane group owning this (e,h) pair
    s += __shfl_xor(s, 1);
    s += __shfl_xor(s, 2);
    s += __shfl_xor(s, 4);

    if ((threadIdx.x & 7) == 0) {
        const int p = f >> 3;          // pair id = e*H + h
        norm_x[p] = s;
        const int e = p >> 2;          // H_ == 4
        const int h = p & 3;
        const int n = index[e];
        // s >= 0 and table pre-zeroed: int-compare == float-compare.
        atomicMax(reinterpret_cast<int*>(max_norm) + (size_t)n * H_ + h, __float_as_int(s));
    }
}

// Pass B: thread per edge; float4 over the H=4 heads.
__global__ void __launch_bounds__(256)
k_output(const float* __restrict__ alpha,
         const int* __restrict__ index,
         const float* __restrict__ max_norm,   // flat [N*H]
         const float* __restrict__ norm_x,     // [E*H]
         const float* __restrict__ natt,       // [H]
         float* __restrict__ out,              // [E*H]
         int E) {
    const int e = blockIdx.x * blockDim.x + threadIdx.x;
    if (e >= E) return;
    const float n0 = natt[0], n1 = natt[1], n2 = natt[2], n3 = natt[3];
    const float g = max_norm[index[e]];        // faithful flat-gather
    const float4 nx = reinterpret_cast<const float4*>(norm_x)[e];
    const float4 al = reinterpret_cast<const float4*>(alpha)[e];
    float4 o;
    o.x = al.x / (n0 * sqrtf(g + nx.x) + EPS_);
    o.y = al.y / (n1 * sqrtf(g + nx.y) + EPS_);
    o.z = al.z / (n2 * sqrtf(g + nx.z) + EPS_);
    o.w = al.w / (n3 * sqrtf(g + nx.w) + EPS_);
    reinterpret_cast<float4*>(out)[e] = o;
}

extern "C" void kernel_launch(void* const* d_in, const int* in_sizes, int n_in,
                              void* d_out, int out_size, void* d_ws, size_t ws_size,
                              hipStream_t stream) {
    const float* x     = (const float*)d_in[0];
    const float* att_l = (const float*)d_in[1];
    const float* att_r = (const float*)d_in[2];
    const float* alpha = (const float*)d_in[3];
    const int*   index = (const int*)d_in[4];

    const int E        = in_sizes[0] / (H_ * D_);
    const int EH       = E * H_;
    const int total_f4 = EH * (D_ / 4);        // 25.6M float4s

    char* wsb = (char*)d_ws;
    const size_t maxnorm_bytes = (size_t)N_NODES * H_ * sizeof(float);   // 800 KB
    float* max_norm = (float*)wsb;
    float* norm_x   = (float*)(wsb + maxnorm_bytes);
    float* natt     = (float*)(wsb + maxnorm_bytes + (size_t)EH * sizeof(float));

    // zero the scatter-max table every call (harness does not re-poison).
    hipMemsetAsync(max_norm, 0, maxnorm_bytes, stream);

    const int b = 256;
    k_norm_scatter<<<(total_f4 + b - 1) / b, b, 0, stream>>>(
        x, index, att_l, att_r, max_norm, norm_x, natt, total_f4);
    k_output<<<(E + b - 1) / b, b, 0, stream>>>(
        alpha, index, max_norm, norm_x, natt, (float*)d_out, E);
}

// Round 3
// 108.356 us; speedup vs baseline: 1.1755x; 1.1755x over previous
//
#include <hip/hip_runtime.h>
#include <math.h>

// LipschitzNorm: E=800000 edges, N=50000 nodes, H=4 heads, D=32 dims (fp32).
// out[e,h] = alpha[e,h] / (natt[h] * sqrt(g[e] + ||x[e,h]||^2) + EPS)
//   natt[h] = 4 * ||concat(att_l[h], att_r[h])||
//   g[e]    = segment_max(||x||^2, index).flat[index[e]]   (faithful view(-1,1) bug)
//
// R3: pass A = coalesced (16B/lane contiguous) AND 8-deep load ILP.
// Block of 256 threads owns 256 pairs (2048 float4s, 32KB): thread t loads
// float4 elements {k*256+t, k=0..7} (8 independent fully-coalesced loads),
// then per-k an 8-lane shfl_xor butterfly (chains independent across k).

static constexpr int   H_        = 4;
static constexpr int   D_        = 32;
static constexpr int   N_NODES   = 50000;
static constexpr float ATT_NORM_ = 4.0f;
static constexpr float EPS_      = 1e-12f;

__global__ void __launch_bounds__(256)
k_norm_scatter(const float4* __restrict__ x4,
               const int* __restrict__ index,
               const float* __restrict__ att_l,
               const float* __restrict__ att_r,
               float* __restrict__ max_norm,   // [N*H], pre-zeroed
               float* __restrict__ norm_x,     // [E*H]
               float* __restrict__ natt,       // [H]
               int n_pairs,                    // EH
               int total_f4) {                 // EH * 8
    if (blockIdx.x == 0 && threadIdx.x < H_) {
        const int h = threadIdx.x;
        float s = 0.f;
        #pragma unroll
        for (int d = 0; d < D_; ++d) {
            const float a = att_l[h * D_ + d];
            const float b = att_r[h * D_ + d];
            s += a * a + b * b;
        }
        natt[h] = ATT_NORM_ * sqrtf(s);
    }

    const int t     = threadIdx.x;
    const int lane  = t & 63;
    const int w     = t >> 6;                    // wave id 0..3
    const int pair0 = blockIdx.x * 256;
    const size_t f0 = (size_t)pair0 * 8;

    // 8 independent coalesced loads (1KB/wave-instruction, block reads 32KB contiguous)
    float4 v[8];
    #pragma unroll
    for (int k = 0; k < 8; ++k) {
        const size_t f = f0 + (size_t)k * 256 + t;
        if (f < (size_t)total_f4) v[k] = x4[f];
        else                      v[k] = make_float4(0.f, 0.f, 0.f, 0.f);
    }

    // per-k squared-sum + 8-lane butterfly; chains independent across k
    float sq[8];
    #pragma unroll
    for (int k = 0; k < 8; ++k) {
        float s = v[k].x * v[k].x + v[k].y * v[k].y + v[k].z * v[k].z + v[k].w * v[k].w;
        s += __shfl_xor(s, 1);
        s += __shfl_xor(s, 2);
        s += __shfl_xor(s, 4);
        sq[k] = s;
    }

    if ((lane & 7) == 0) {
        const int sub = lane >> 3;               // 0..7
        #pragma unroll
        for (int k = 0; k < 8; ++k) {
            const int p = pair0 + k * 32 + w * 8 + sub;   // pair id = e*H + h
            if (p < n_pairs) {
                norm_x[p] = sq[k];
                const int e = p >> 2;            // H_ == 4
                const int h = p & 3;
                const int n = index[e];
                // sq >= 0 and table pre-zeroed: int-compare == float-compare.
                atomicMax(reinterpret_cast<int*>(max_norm) + (size_t)n * H_ + h,
                          __float_as_int(sq[k]));
            }
        }
    }
}

// Pass B: thread per edge; float4 over the H=4 heads.
__global__ void __launch_bounds__(256)
k_output(const float* __restrict__ alpha,
         const int* __restrict__ index,
         const float* __restrict__ max_norm,   // flat [N*H]
         const float* __restrict__ norm_x,     // [E*H]
         const float* __restrict__ natt,       // [H]
         float* __restrict__ out,              // [E*H]
         int E) {
    const int e = blockIdx.x * blockDim.x + threadIdx.x;
    if (e >= E) return;
    const float n0 = natt[0], n1 = natt[1], n2 = natt[2], n3 = natt[3];
    const float g = max_norm[index[e]];        // faithful flat-gather
    const float4 nx = reinterpret_cast<const float4*>(norm_x)[e];
    const float4 al = reinterpret_cast<const float4*>(alpha)[e];
    float4 o;
    o.x = al.x / (n0 * sqrtf(g + nx.x) + EPS_);
    o.y = al.y / (n1 * sqrtf(g + nx.y) + EPS_);
    o.z = al.z / (n2 * sqrtf(g + nx.z) + EPS_);
    o.w = al.w / (n3 * sqrtf(g + nx.w) + EPS_);
    reinterpret_cast<float4*>(out)[e] = o;
}

extern "C" void kernel_launch(void* const* d_in, const int* in_sizes, int n_in,
                              void* d_out, int out_size, void* d_ws, size_t ws_size,
                              hipStream_t stream) {
    const float* x     = (const float*)d_in[0];
    const float* att_l = (const float*)d_in[1];
    const float* att_r = (const float*)d_in[2];
    const float* alpha = (const float*)d_in[3];
    const int*   index = (const int*)d_in[4];

    const int E        = in_sizes[0] / (H_ * D_);
    const int EH       = E * H_;
    const int total_f4 = EH * (D_ / 4);        // 25.6M float4s

    char* wsb = (char*)d_ws;
    const size_t maxnorm_bytes = (size_t)N_NODES * H_ * sizeof(float);   // 800 KB
    float* max_norm = (float*)wsb;
    float* norm_x   = (float*)(wsb + maxnorm_bytes);
    float* natt     = (float*)(wsb + maxnorm_bytes + (size_t)EH * sizeof(float));

    // zero the scatter-max table every call (harness does not re-poison).
    hipMemsetAsync(max_norm, 0, maxnorm_bytes, stream);

    const int b = 256;
    const int blocksA = (EH + 255) / 256;      // 256 pairs per block
    k_norm_scatter<<<blocksA, b, 0, stream>>>(
        (const float4*)x, index, att_l, att_r, max_norm, norm_x, natt, EH, total_f4);
    k_output<<<(E + b - 1) / b, b, 0, stream>>>(
        alpha, index, max_norm, norm_x, natt, (float*)d_out, E);
}

// Round 5
// 98.484 us; speedup vs baseline: 1.2934x; 1.1002x over previous
//
#include <hip/hip_runtime.h>
#include <math.h>

// LipschitzNorm: E=800000 edges, N=50000 nodes, H=4 heads, D=32 dims (fp32).
// out[e,h] = alpha[e,h] / (natt[h] * sqrt(g[e] + ||x[e,h]||^2) + EPS)
//   natt[h] = 4 * ||concat(att_l[h], att_r[h])||
//   g[e]    = segment_max(||x||^2, index).flat[index[e]]   (faithful view(-1,1) bug)
//
// R5 insight: the flat-gather only ever reads table positions < N (=50000),
// i.e. nodes n < N/H (=12500). AtomicMax from edges with index >= 12500 can
// never influence the output -> skip them (3.2M -> ~0.8M atomics, table
// shrinks 800KB -> 200KB). Structure otherwise = R1 (105us baseline): pass A
// thread-per-(e,h) with 8 unrolled float4 loads, pass B thread-per-edge.

static constexpr int   H_        = 4;
static constexpr int   D_        = 32;
static constexpr int   N_NODES   = 50000;
static constexpr int   N_LIVE    = N_NODES / H_;   // 12500: only these nodes are gathered
static constexpr float ATT_NORM_ = 4.0f;
static constexpr float EPS_      = 1e-12f;

__global__ void __launch_bounds__(256)
k_norm_scatter(const float* __restrict__ x,
               const int* __restrict__ index,
               const float* __restrict__ att_l,
               const float* __restrict__ att_r,
               float* __restrict__ max_norm,   // [N_NODES] flat floats (only pos<50000 used)
               float* __restrict__ norm_x,     // [E*H]
               float* __restrict__ natt,       // [H]
               int EH) {
    if (blockIdx.x == 0 && threadIdx.x < H_) {
        const int h = threadIdx.x;
        float s = 0.f;
        #pragma unroll
        for (int d = 0; d < D_; ++d) {
            const float a = att_l[h * D_ + d];
            const float b = att_r[h * D_ + d];
            s += a * a + b * b;
        }
        natt[h] = ATT_NORM_ * sqrtf(s);
    }
    const int p = blockIdx.x * blockDim.x + threadIdx.x;   // pair id = e*H + h
    if (p >= EH) return;

    const float4* xv = reinterpret_cast<const float4*>(x) + (size_t)p * (D_ / 4);
    float s = 0.f;
    #pragma unroll
    for (int j = 0; j < D_ / 4; ++j) {
        const float4 v = xv[j];
        s += v.x * v.x + v.y * v.y + v.z * v.z + v.w * v.w;
    }
    norm_x[p] = s;

    const int e = p >> 2;      // H_ == 4
    const int h = p & 3;
    const int n = index[e];
    // Only nodes n < N_LIVE are ever gathered (flat view bug). Skip the rest.
    if (n < N_LIVE) {
        // s >= 0 and table pre-zeroed: int-compare == float-compare.
        atomicMax(reinterpret_cast<int*>(max_norm) + n * H_ + h, __float_as_int(s));
    }
}

// Pass B: thread per edge; float4 over the H=4 heads.
__global__ void __launch_bounds__(256)
k_output(const float* __restrict__ alpha,
         const int* __restrict__ index,
         const float* __restrict__ max_norm,   // flat, first 50000 valid
         const float* __restrict__ norm_x,     // [E*H]
         const float* __restrict__ natt,       // [H]
         float* __restrict__ out,              // [E*H]
         int E) {
    const int e = blockIdx.x * blockDim.x + threadIdx.x;
    if (e >= E) return;
    const float n0 = natt[0], n1 = natt[1], n2 = natt[2], n3 = natt[3];
    const float g = max_norm[index[e]];        // faithful flat-gather (< 50000)
    const float4 nx = reinterpret_cast<const float4*>(norm_x)[e];
    const float4 al = reinterpret_cast<const float4*>(alpha)[e];
    float4 o;
    o.x = al.x / (n0 * sqrtf(g + nx.x) + EPS_);
    o.y = al.y / (n1 * sqrtf(g + nx.y) + EPS_);
    o.z = al.z / (n2 * sqrtf(g + nx.z) + EPS_);
    o.w = al.w / (n3 * sqrtf(g + nx.w) + EPS_);
    reinterpret_cast<float4*>(out)[e] = o;
}

extern "C" void kernel_launch(void* const* d_in, const int* in_sizes, int n_in,
                              void* d_out, int out_size, void* d_ws, size_t ws_size,
                              hipStream_t stream) {
    const float* x     = (const float*)d_in[0];
    const float* att_l = (const float*)d_in[1];
    const float* att_r = (const float*)d_in[2];
    const float* alpha = (const float*)d_in[3];
    const int*   index = (const int*)d_in[4];

    const int E  = in_sizes[0] / (H_ * D_);
    const int EH = E * H_;

    char* wsb = (char*)d_ws;
    const size_t table_bytes = (size_t)N_NODES * sizeof(float);   // 200 KB (flat pos < 50000)
    float* max_norm = (float*)wsb;
    float* norm_x   = (float*)(wsb + table_bytes);
    float* natt     = (float*)(wsb + table_bytes + (size_t)EH * sizeof(float));

    // zero the (live part of the) scatter-max table every call.
    hipMemsetAsync(max_norm, 0, table_bytes, stream);

    const int b = 256;
    k_norm_scatter<<<(EH + b - 1) / b, b, 0, stream>>>(
        x, index, att_l, att_r, max_norm, norm_x, natt, EH);
    k_output<<<(E + b - 1) / b, b, 0, stream>>>(
        alpha, index, max_norm, norm_x, natt, (float*)d_out, E);
}